// Round 14
// baseline (562.818 us; speedup 1.0000x reference)
//
#include <hip/hip_runtime.h>

typedef unsigned short u16;
typedef __bf16 bfv8 __attribute__((ext_vector_type(8)));     // MFMA A/B fragment (4 VGPRs)
typedef float f32x16 __attribute__((ext_vector_type(16)));   // MFMA 32x32 C/D fragment

#define HDIM 512
#define NHEAD 8
#define GNUM 64
#define CNUM 10
#define SLOPE 0.01f
#define BNEPS 1e-5f
#define PSPLIT 8

__device__ __forceinline__ float b2f(u16 u) { return __uint_as_float(((unsigned)u) << 16); }
__device__ __forceinline__ u16 f2b(float f) {              // RNE f32->bf16
    unsigned u = __float_as_uint(f);
    u += 0x7FFFu + ((u >> 16) & 1u);
    return (u16)(u >> 16);
}
__device__ __forceinline__ void splitbf(float v, u16& hi, u16& lo) {
    u16 h = f2b(v);
    hi = h;
    lo = f2b(v - b2f(h));
}

__global__ void sentinel_kernel(float* out, int n, float val) {
    int i = blockIdx.x * 256 + threadIdx.x;
    if (i < n) out[i] = val;
}

__global__ void zero_i32_kernel(int* __restrict__ p, int n) {
    int i = blockIdx.x * 256 + threadIdx.x;
    if (i < n) p[i] = 0;
}

// ---- zero the padded tail rows [N, N128) of all GEMM A-inputs (ws is re-poisoned
// every launch). Lets the K-loop run guard-free.
__global__ void ztail_kernel(u16* __restrict__ xinh, u16* __restrict__ xinl, int F0,
                             u16* __restrict__ x0h, u16* __restrict__ x0l,
                             u16* __restrict__ x1h, u16* __restrict__ x1l,
                             u16* __restrict__ x2h, u16* __restrict__ x2l,
                             u16* __restrict__ x3h, u16* __restrict__ x3l, int N) {
    int row = N + blockIdx.x;
    int b = blockIdx.y;
    int t = threadIdx.x;
    if (b < 2) {
        u16* p = (b == 0) ? xinh : xinl;
        for (int c = t; c < F0; c += 256) p[(size_t)row * F0 + c] = 0;
    } else {
        u16* ps[8] = {x0h, x0l, x1h, x1l, x2h, x2l, x3h, x3l};
        u16* p = ps[b - 2];
        for (int c = t; c < HDIM; c += 256) p[(size_t)row * HDIM + c] = 0;
    }
}

// ---- weight transpose+split via LDS tiles: W[K][512] f32 -> Whi/Wlo[n][K] bf16 ----
__device__ __forceinline__ void wsplit_body(const float* __restrict__ W, u16* __restrict__ Whi,
                                            u16* __restrict__ Wlo, int K) {
    __shared__ float tile[64][65];
    int kb = blockIdx.x * 64, nb = blockIdx.y * 64;
    int t = threadIdx.x;
    #pragma unroll
    for (int i = 0; i < 16; i++) {
        int idx = t + i * 256;
        int r = idx >> 6, c = idx & 63;
        tile[r][c] = W[(size_t)(kb + r) * HDIM + nb + c];
    }
    __syncthreads();
    #pragma unroll
    for (int i = 0; i < 16; i++) {
        int idx = t + i * 256;
        int r = idx >> 6, c = idx & 63;
        float v = tile[c][r];
        u16 hi, lo;
        splitbf(v, hi, lo);
        size_t o = (size_t)(nb + r) * K + kb + c;
        Whi[o] = hi;
        Wlo[o] = lo;
    }
}

__global__ void wsplit_kernel(const float* __restrict__ W, u16* __restrict__ Whi,
                              u16* __restrict__ Wlo, int K) {
    wsplit_body(W, Whi, Wlo, K);
}

// W1,W2,W3 (all K=512) in one launch, grid.z selects layer
__global__ void wsplit3_kernel(const float* __restrict__ W1, const float* __restrict__ W2,
                               const float* __restrict__ W3,
                               u16* __restrict__ h1, u16* __restrict__ l1,
                               u16* __restrict__ h2, u16* __restrict__ l2,
                               u16* __restrict__ h3, u16* __restrict__ l3) {
    const float* W = (blockIdx.z == 0) ? W1 : (blockIdx.z == 1) ? W2 : W3;
    u16* Wh = (blockIdx.z == 0) ? h1 : (blockIdx.z == 1) ? h2 : h3;
    u16* Wl = (blockIdx.z == 0) ? l1 : (blockIdx.z == 1) ? l2 : l3;
    wsplit_body(W, Wh, Wl, HDIM);
}

// ---- activation split: f32 -> hi/lo bf16 ----
__global__ void xsplit_kernel(const float* __restrict__ x, u16* __restrict__ hi,
                              u16* __restrict__ lo, int n) {
    int i = blockIdx.x * 256 + threadIdx.x;
    if (i < n) splitbf(x[i], hi[i], lo[i]);
}

// ---- split-bf16 MFMA GEMM (32x32x16), tile 128x64, 3-term, BARRIER-FREE K-loop ----
// XCD-swizzled 1-D grid keeps each XCD's A-slice L2-resident (verified FETCH 87->15MB).
// No LDS staging: A/B fragments (16B/lane, aligned) stream straight from L2 into MFMA;
// with no __syncthreads the compiler pipelines loads across iterations freely.
// A-inputs are tail-padded (ztail) so the loop needs no row guards.
__global__ __launch_bounds__(256, 2) void gemm_split(const u16* __restrict__ Ah,
                                                     const u16* __restrict__ Al,
                                                     const u16* __restrict__ Bh,
                                                     const u16* __restrict__ Bl,
                                                     const float* __restrict__ a_src,
                                                     const float* __restrict__ a_dst,
                                                     u16* __restrict__ Chi,
                                                     float* __restrict__ es,
                                                     float* __restrict__ ed, int M, int K) {
    __shared__ float sE[128][2][2]; // [row][wn-half][es/ed]
    int t = threadIdx.x;
    int id = blockIdx.x;
    int nrt = gridDim.x >> 3;
    int w = (id & 7) * nrt + (id >> 3);
    int rt = w >> 3, ct = w & 7;
    int bm = rt * 128, bn = ct * 64;
    int hh = ct;                    // head index (64 cols per head)
    int wv = t >> 6, lane = t & 63;
    int wm = (wv >> 1) * 64, wn = (wv & 1) * 32;
    int l32 = lane & 31, kh = lane >> 5;

    f32x16 acc[2];
    for (int m = 0; m < 2; m++)
        for (int r = 0; r < 16; r++) acc[m][r] = 0.f;

    // per-lane fragment pointers: A[m = l32][k = kh*8 + j]
    const u16* pAh0 = Ah + (size_t)(bm + wm + l32) * K + kh * 8;
    const u16* pAl0 = Al + (size_t)(bm + wm + l32) * K + kh * 8;
    const u16* pAh1 = pAh0 + (size_t)32 * K;
    const u16* pAl1 = pAl0 + (size_t)32 * K;
    const u16* pBh = Bh + (size_t)(bn + wn + l32) * K + kh * 8;
    const u16* pBl = Bl + (size_t)(bn + wn + l32) * K + kh * 8;

    #pragma unroll 2
    for (int kt = 0; kt < K; kt += 32) {
        bfv8 a0h0 = *(const bfv8*)(pAh0 + kt);
        bfv8 a0l0 = *(const bfv8*)(pAl0 + kt);
        bfv8 a1h0 = *(const bfv8*)(pAh1 + kt);
        bfv8 a1l0 = *(const bfv8*)(pAl1 + kt);
        bfv8 bh0  = *(const bfv8*)(pBh + kt);
        bfv8 bl0  = *(const bfv8*)(pBl + kt);
        bfv8 a0h1 = *(const bfv8*)(pAh0 + kt + 16);
        bfv8 a0l1 = *(const bfv8*)(pAl0 + kt + 16);
        bfv8 a1h1 = *(const bfv8*)(pAh1 + kt + 16);
        bfv8 a1l1 = *(const bfv8*)(pAl1 + kt + 16);
        bfv8 bh1  = *(const bfv8*)(pBh + kt + 16);
        bfv8 bl1  = *(const bfv8*)(pBl + kt + 16);
        acc[0] = __builtin_amdgcn_mfma_f32_32x32x16_bf16(a0l0, bh0, acc[0], 0, 0, 0);
        acc[1] = __builtin_amdgcn_mfma_f32_32x32x16_bf16(a1l0, bh0, acc[1], 0, 0, 0);
        acc[0] = __builtin_amdgcn_mfma_f32_32x32x16_bf16(a0h0, bl0, acc[0], 0, 0, 0);
        acc[1] = __builtin_amdgcn_mfma_f32_32x32x16_bf16(a1h0, bl0, acc[1], 0, 0, 0);
        acc[0] = __builtin_amdgcn_mfma_f32_32x32x16_bf16(a0h0, bh0, acc[0], 0, 0, 0);
        acc[1] = __builtin_amdgcn_mfma_f32_32x32x16_bf16(a1h0, bh0, acc[1], 0, 0, 0);
        acc[0] = __builtin_amdgcn_mfma_f32_32x32x16_bf16(a0l1, bh1, acc[0], 0, 0, 0);
        acc[1] = __builtin_amdgcn_mfma_f32_32x32x16_bf16(a1l1, bh1, acc[1], 0, 0, 0);
        acc[0] = __builtin_amdgcn_mfma_f32_32x32x16_bf16(a0h1, bl1, acc[0], 0, 0, 0);
        acc[1] = __builtin_amdgcn_mfma_f32_32x32x16_bf16(a1h1, bl1, acc[1], 0, 0, 0);
        acc[0] = __builtin_amdgcn_mfma_f32_32x32x16_bf16(a0h1, bh1, acc[0], 0, 0, 0);
        acc[1] = __builtin_amdgcn_mfma_f32_32x32x16_bf16(a1h1, bh1, acc[1], 0, 0, 0);
    }
    float asv = a_src[hh * 64 + wn + l32];
    float adv = a_dst[hh * 64 + wn + l32];
    // C/D layout (m74/m101-verified): col=lane&31, row=(reg&3)+8*(reg>>2)+4*(lane>>5)
    int col = bn + wn + l32;
    #pragma unroll
    for (int mt = 0; mt < 2; mt++)
        #pragma unroll
        for (int r = 0; r < 16; r++) {
            float v = acc[mt][r];
            int lr = wm + mt * 32 + (r & 3) + 8 * (r >> 2) + 4 * kh;   // block-local row
            int row = bm + lr;
            if (row < M) Chi[(size_t)row * HDIM + col] = f2b(v);
            float s1 = v * asv, s2 = v * adv;
            #pragma unroll
            for (int msk = 1; msk <= 16; msk <<= 1) {
                s1 += __shfl_xor(s1, msk);
                s2 += __shfl_xor(s2, msk);
            }
            if (l32 == 0) { sE[lr][wv & 1][0] = s1; sE[lr][wv & 1][1] = s2; }
        }
    __syncthreads();
    if (t < 128) {
        int row = bm + t;
        if (row < M) {
            es[row * NHEAD + hh] = sE[t][0][0] + sE[t][1][0];
            ed[row * NHEAD + hh] = sE[t][0][1] + sE[t][1][1];
        }
    }
}

// ---- counting sort of edges by dst ----
__global__ void hist_kernel(const int* __restrict__ ei, int* __restrict__ deg, int E) {
    int e = blockIdx.x * 256 + threadIdx.x;
    if (e < E) atomicAdd(&deg[ei[E + e]], 1);
}

__global__ void scan_kernel(const int* __restrict__ deg, int* __restrict__ offs,
                            int* __restrict__ cursor, int n) {
    __shared__ int lds[1024];
    int t = threadIdx.x;
    const int CH = 16;
    int base = t * CH;
    int local[CH];
    int s = 0;
    for (int i = 0; i < CH; i++) {
        int idx = base + i;
        local[i] = (idx < n) ? deg[idx] : 0;
        s += local[i];
    }
    lds[t] = s;
    __syncthreads();
    for (int off = 1; off < 1024; off <<= 1) {
        int v = lds[t];
        int add = (t >= off) ? lds[t - off] : 0;
        __syncthreads();
        lds[t] = v + add;
        __syncthreads();
    }
    int ex = (t == 0) ? 0 : lds[t - 1];
    for (int i = 0; i < CH; i++) {
        int idx = base + i;
        if (idx < n) { offs[idx] = ex; cursor[idx] = ex; ex += local[i]; }
    }
}

__global__ void scatter_kernel(const int* __restrict__ ei, int* __restrict__ cursor,
                               int* __restrict__ ssrc, int E) {
    int e = blockIdx.x * 256 + threadIdx.x;
    if (e < E) {
        int p = atomicAdd(&cursor[ei[E + e]], 1);
        ssrc[p] = ei[e];
    }
}

// ---- fused per-dst ONLINE softmax + aggregation + bias + ELU (+ residual) ----
__global__ void agg_kernel(const u16* __restrict__ hh_buf, const float* __restrict__ es,
                           const float* __restrict__ ed, const int* __restrict__ offs,
                           const int* __restrict__ deg, const int* __restrict__ ssrc,
                           const float* __restrict__ bias,
                           u16* __restrict__ ohi, u16* __restrict__ olo,
                           const u16* __restrict__ rhi, const u16* __restrict__ rlo,
                           u16* __restrict__ qhi, u16* __restrict__ qlo, int n) {
    int node = blockIdx.x * 4 + (threadIdx.x >> 6);
    int lane = threadIdx.x & 63;
    if (node >= n) return;
    int hh = lane >> 3, f = lane * 8;
    float edv = ed[node * NHEAD + hh];
    int st = offs[node], cnt = deg[node];

    float m = -INFINITY, den = 0.f;
    float acc[8] = {0.f, 0.f, 0.f, 0.f, 0.f, 0.f, 0.f, 0.f};
    int i = 0;
    for (; i + 2 <= cnt; i += 2) {
        int s0 = ssrc[st + i];
        int s1 = ssrc[st + i + 1];
        float e0 = es[s0 * NHEAD + hh] + edv;
        float e1 = es[s1 * NHEAD + hh] + edv;
        union { int4 v; u16 u[8]; } U0, U1;
        U0.v = *(const int4*)(hh_buf + (size_t)s0 * HDIM + f);
        U1.v = *(const int4*)(hh_buf + (size_t)s1 * HDIM + f);
        e0 = e0 > 0.f ? e0 : SLOPE * e0;
        e1 = e1 > 0.f ? e1 : SLOPE * e1;
        float mn = fmaxf(m, fmaxf(e0, e1));
        float sc = __expf(m - mn);       // first iter: exp(-inf)=0
        float w0 = __expf(e0 - mn);
        float w1 = __expf(e1 - mn);
        den = den * sc + w0 + w1;
        #pragma unroll
        for (int j = 0; j < 8; j++)
            acc[j] = acc[j] * sc + w0 * b2f(U0.u[j]) + w1 * b2f(U1.u[j]);
        m = mn;
    }
    if (i < cnt) {
        int s0 = ssrc[st + i];
        float e0 = es[s0 * NHEAD + hh] + edv;
        union { int4 v; u16 u[8]; } U0;
        U0.v = *(const int4*)(hh_buf + (size_t)s0 * HDIM + f);
        e0 = e0 > 0.f ? e0 : SLOPE * e0;
        float mn = fmaxf(m, e0);
        float sc = __expf(m - mn);
        float w0 = __expf(e0 - mn);
        den = den * sc + w0;
        #pragma unroll
        for (int j = 0; j < 8; j++) acc[j] = acc[j] * sc + w0 * b2f(U0.u[j]);
    }
    float inv = den > 0.f ? 1.f / den : 0.f;
    union { int4 v; u16 u[8]; } Hi, Lo;
    float o[8];
    #pragma unroll
    for (int j = 0; j < 8; j++) {
        float v = acc[j] * inv + bias[f + j];
        o[j] = v > 0.f ? v : __expf(v) - 1.f;  // ELU
        splitbf(o[j], Hi.u[j], Lo.u[j]);
    }
    size_t base = (size_t)node * HDIM + f;
    *(int4*)&ohi[base] = Hi.v;
    *(int4*)&olo[base] = Lo.v;
    if (rhi) {
        union { int4 v; u16 u[8]; } Rh, Rl, Qh, Ql;
        Rh.v = *(const int4*)&rhi[base];
        Rl.v = *(const int4*)&rlo[base];
        #pragma unroll
        for (int j = 0; j < 8; j++) {
            float v = o[j] + b2f(Rh.u[j]) + b2f(Rl.u[j]);
            splitbf(v, Qh.u[j], Ql.u[j]);
        }
        *(int4*)&qhi[base] = Qh.v;
        *(int4*)&qlo[base] = Ql.v;
    }
}

// ---- pooling stage 1: partial segment-max over bf16-hi ----
__global__ void pool1_kernel(const u16* __restrict__ s0h, const u16* __restrict__ s1h,
                             const u16* __restrict__ s2h, const u16* __restrict__ s3h,
                             const int* __restrict__ batch, float* __restrict__ partial, int n) {
    int g = blockIdx.x, b = blockIdx.y, c = blockIdx.z;
    int t = threadIdx.x;
    const u16* hs[4] = {s0h, s1h, s2h, s3h};
    const u16* sh = hs[b];
    int lo = 0, hi = n;
    while (lo < hi) { int mid = (lo + hi) >> 1; if (batch[mid] < g) lo = mid + 1; else hi = mid; }
    int start = lo;
    lo = start; hi = n;
    while (lo < hi) { int mid = (lo + hi) >> 1; if (batch[mid] < g + 1) lo = mid + 1; else hi = mid; }
    int end = lo;
    int len = end - start;
    int cb = start + (int)(((long long)len * c) / PSPLIT);
    int ce = start + (int)(((long long)len * (c + 1)) / PSPLIT);
    float mx0 = -INFINITY, mx1 = -INFINITY;
    for (int i = cb; i < ce; i++) {
        size_t ro = (size_t)i * HDIM;
        mx0 = fmaxf(mx0, b2f(sh[ro + t]));
        mx1 = fmaxf(mx1, b2f(sh[ro + 256 + t]));
    }
    size_t pb = (size_t)((g * 4 + b) * PSPLIT + c) * 512;
    partial[pb + t] = mx0;
    partial[pb + 256 + t] = mx1;
}

// ---- pooling stage 2: reduce PSPLIT partials, clamp empties; fused z init ----
__global__ void pool2_kernel(const float* __restrict__ partial, float* __restrict__ pooled,
                             const float* __restrict__ mb1, float* __restrict__ z) {
    int g = blockIdx.x, b = blockIdx.y;
    int t = threadIdx.x;
    float mx0 = -INFINITY, mx1 = -INFINITY;
    for (int c = 0; c < PSPLIT; c++) {
        size_t pb = (size_t)((g * 4 + b) * PSPLIT + c) * 512;
        mx0 = fmaxf(mx0, partial[pb + t]);
        mx1 = fmaxf(mx1, partial[pb + 256 + t]);
    }
    if (!isfinite(mx0)) mx0 = 0.f;
    if (!isfinite(mx1)) mx1 = 0.f;
    pooled[g * 2048 + b * 512 + t] = mx0;
    pooled[g * 2048 + b * 512 + 256 + t] = mx1;
    if (t < 128) {                       // fused: z[g][b*128 + t] = mb1[...]
        int col = b * 128 + t;
        z[g * HDIM + col] = mb1[col];
    }
}

// ---- MLP layer 1, split-K: z[64,512] += pooled[64,2048-chunk] @ mW1-chunk ----
__global__ __launch_bounds__(256) void mlp1_splitk(const float* __restrict__ pooled,
                                                   const float* __restrict__ mW1,
                                                   float* __restrict__ z) {
    __shared__ float sp[256];
    int g = blockIdx.x, kc = blockIdx.y * 256;
    int t = threadIdx.x;
    sp[t] = pooled[g * 2048 + kc + t];
    __syncthreads();
    float acc0 = 0.f, acc1 = 0.f;
    const float* wp = mW1 + (size_t)kc * HDIM;
    #pragma unroll 8
    for (int k = 0; k < 256; k++) {
        float pv = sp[k];
        acc0 += pv * wp[(size_t)k * HDIM + t];
        acc1 += pv * wp[(size_t)k * HDIM + 256 + t];
    }
    atomicAdd(&z[g * HDIM + t], acc0);
    atomicAdd(&z[g * HDIM + 256 + t], acc1);
}

// ---- BatchNorm (batch stats over 64 graphs) + ReLU ----
__global__ void bn_relu_kernel(const float* __restrict__ z, const float* __restrict__ gammaf,
                               const float* __restrict__ betaf, float* __restrict__ zn) {
    int col = blockIdx.x;
    int g = threadIdx.x;   // 64 = one wave
    float v = z[g * HDIM + col];
    float s = v;
    for (int o = 32; o > 0; o >>= 1) s += __shfl_xor(s, o);
    float mu = s * (1.f / 64.f);
    float d = v - mu;
    float s2 = d * d;
    for (int o = 32; o > 0; o >>= 1) s2 += __shfl_xor(s2, o);
    float var = s2 * (1.f / 64.f);
    float o = d * rsqrtf(var + BNEPS) * gammaf[col] + betaf[col];
    zn[g * HDIM + col] = fmaxf(o, 0.f);
}

// ---- final: out[g][c] = zn[g,:] . mW2[:,c] + mb2[c]; one wave per output ----
__global__ void final_kernel(const float* __restrict__ zn, const float* __restrict__ mW2,
                             const float* __restrict__ mb2, float* __restrict__ out) {
    int g = blockIdx.x, c = blockIdx.y;
    int lane = threadIdx.x;   // 64
    float acc = 0.f;
    #pragma unroll
    for (int k = lane; k < HDIM; k += 64) acc += zn[g * HDIM + k] * mW2[k * CNUM + c];
    for (int o = 32; o > 0; o >>= 1) acc += __shfl_down(acc, o);
    if (lane == 0) out[g * CNUM + c] = acc + mb2[c];
}

extern "C" void kernel_launch(void* const* d_in, const int* in_sizes, int n_in,
                              void* d_out, int out_size, void* d_ws, size_t ws_size,
                              hipStream_t stream) {
    const float* x = (const float*)d_in[0];
    const int* ei = (const int*)d_in[1];
    const int* batch = (const int*)d_in[2];
    const float* Wm[4] = {(const float*)d_in[3], (const float*)d_in[7],
                          (const float*)d_in[11], (const float*)d_in[15]};
    const float* Asc[4] = {(const float*)d_in[4], (const float*)d_in[8],
                           (const float*)d_in[12], (const float*)d_in[16]};
    const float* Adc[4] = {(const float*)d_in[5], (const float*)d_in[9],
                           (const float*)d_in[13], (const float*)d_in[17]};
    const float* Bb[4] = {(const float*)d_in[6], (const float*)d_in[10],
                          (const float*)d_in[14], (const float*)d_in[18]};
    const float* mW1 = (const float*)d_in[19];
    const float* mb1 = (const float*)d_in[20];
    const float* gammaf = (const float*)d_in[21];
    const float* betaf = (const float*)d_in[22];
    const float* mW2 = (const float*)d_in[23];
    const float* mb2 = (const float*)d_in[24];
    (void)n_in;

    int N = in_sizes[2];
    int E = in_sizes[1] / 2;
    int F0 = in_sizes[0] / N;
    int nrt = (N + 127) / 128;
    int N128 = nrt * 128;                               // padded rows for guard-free GEMM

    // ---- workspace carve (256B-aligned) ----
    char* p = (char*)d_ws;
    auto alloc = [&](size_t bytes) -> char* {
        char* r = p;
        p += (bytes + 255) & ~(size_t)255;
        return r;
    };
    u16 *Wh[4], *Wl[4];
    Wh[0] = (u16*)alloc((size_t)HDIM * F0 * 2);
    Wl[0] = (u16*)alloc((size_t)HDIM * F0 * 2);
    for (int l = 1; l < 4; l++) {
        Wh[l] = (u16*)alloc((size_t)HDIM * HDIM * 2);
        Wl[l] = (u16*)alloc((size_t)HDIM * HDIM * 2);
    }
    u16* xinh = (u16*)alloc((size_t)N128 * F0 * 2);
    u16* xinl = (u16*)alloc((size_t)N128 * F0 * 2);
    u16* hhi = (u16*)alloc((size_t)N * HDIM * 2);       // h of current layer (bf16-hi only)
    u16 *xh[4], *xl[4];                                 // x0..x3 as hi/lo bf16 pairs (padded)
    for (int l = 0; l < 4; l++) {
        xh[l] = (u16*)alloc((size_t)N128 * HDIM * 2);
        xl[l] = (u16*)alloc((size_t)N128 * HDIM * 2);
    }
    float* es = (float*)alloc((size_t)N * NHEAD * 4);
    float* ed = (float*)alloc((size_t)N * NHEAD * 4);
    int* deg = (int*)alloc((size_t)N * 4);
    int* offs = (int*)alloc((size_t)N * 4);
    int* cursor = (int*)alloc((size_t)N * 4);
    int* ssrc = (int*)alloc((size_t)E * 4);
    float* partial = (float*)alloc((size_t)GNUM * 4 * PSPLIT * 512 * 4);
    float* pooled = (float*)alloc((size_t)GNUM * 4 * HDIM * 4);
    float* z = (float*)alloc((size_t)GNUM * HDIM * 4);
    float* zn = (float*)alloc((size_t)GNUM * HDIM * 4);

    if ((size_t)(p - (char*)d_ws) > ws_size) {
        sentinel_kernel<<<(out_size + 255) / 256, 256, 0, stream>>>((float*)d_out, out_size, 999.f);
        return;
    }

    // ---- weight transpose+split, input split, tail zero ----
    {
        dim3 wg0(F0 / 64, HDIM / 64);
        wsplit_kernel<<<wg0, 256, 0, stream>>>(Wm[0], Wh[0], Wl[0], F0);
        dim3 wg3(HDIM / 64, HDIM / 64, 3);
        wsplit3_kernel<<<wg3, 256, 0, stream>>>(Wm[1], Wm[2], Wm[3],
                                                Wh[1], Wl[1], Wh[2], Wl[2], Wh[3], Wl[3]);
    }
    xsplit_kernel<<<(N * F0 + 255) / 256, 256, 0, stream>>>(x, xinh, xinl, N * F0);
    if (N128 > N) {
        dim3 zt(N128 - N, 10);
        ztail_kernel<<<zt, 256, 0, stream>>>(xinh, xinl, F0, xh[0], xl[0], xh[1], xl[1],
                                             xh[2], xl[2], xh[3], xl[3], N);
    }

    // ---- counting sort of edges by dst ----
    zero_i32_kernel<<<(N + 255) / 256, 256, 0, stream>>>(deg, N);
    hist_kernel<<<(E + 255) / 256, 256, 0, stream>>>(ei, deg, E);
    scan_kernel<<<1, 1024, 0, stream>>>(deg, offs, cursor, N);
    scatter_kernel<<<(E + 255) / 256, 256, 0, stream>>>(ei, cursor, ssrc, E);

    // ---- 4 GAT layers ----
    const u16* linh[4] = {xinh, xh[0], xh[1], xh[3]};
    const u16* linl[4] = {xinl, xl[0], xl[1], xl[3]};
    int lK[4] = {F0, HDIM, HDIM, HDIM};
    // layer outputs: L0->x0, L1->x1, L2->x2 (+x3 residual), L3->xt (aliases x0, dead)
    u16* louth[4] = {xh[0], xh[1], xh[2], xh[0]};
    u16* loutl[4] = {xl[0], xl[1], xl[2], xl[0]};
    int gemm_blocks = nrt * 8;                          // 1-D, XCD-swizzled inside
    int agg_blocks = (N + 3) / 4;
    for (int L = 0; L < 4; L++) {
        gemm_split<<<gemm_blocks, 256, 0, stream>>>(linh[L], linl[L], Wh[L], Wl[L],
                                                    Asc[L], Adc[L], hhi, es, ed, N, lK[L]);
        const u16* rh = (L == 2) ? xh[0] : nullptr;
        const u16* rl = (L == 2) ? xl[0] : nullptr;
        u16* qh = (L == 2) ? xh[3] : nullptr;
        u16* ql = (L == 2) ? xl[3] : nullptr;
        agg_kernel<<<agg_blocks, 256, 0, stream>>>(hhi, es, ed, offs, deg, ssrc, Bb[L],
                                                   louth[L], loutl[L], rh, rl, qh, ql, N);
    }

    // ---- pooling (two-stage, hi-only): concat order (xt, x1, x2, x3) ----
    dim3 pool1_grid(GNUM, 4, PSPLIT);
    pool1_kernel<<<pool1_grid, 256, 0, stream>>>(xh[0], xh[1], xh[2], xh[3],
                                                 batch, partial, N);
    dim3 pool2_grid(GNUM, 4);
    pool2_kernel<<<pool2_grid, 256, 0, stream>>>(partial, pooled, mb1, z);

    // ---- MLP head: split-K accumulate, BN+ReLU, final ----
    dim3 mlp_grid(GNUM, 8);
    mlp1_splitk<<<mlp_grid, 256, 0, stream>>>(pooled, mW1, z);
    bn_relu_kernel<<<HDIM, 64, 0, stream>>>(z, gammaf, betaf, zn);
    dim3 final_grid(GNUM, CNUM);
    final_kernel<<<final_grid, 64, 0, stream>>>(zn, mW2, mb2, (float*)d_out);
}

// Round 16
// 402.484 us; speedup vs baseline: 1.3984x; 1.3984x over previous
//
#include <hip/hip_runtime.h>

typedef unsigned short u16;
typedef __bf16 bfv8 __attribute__((ext_vector_type(8)));     // MFMA A/B fragment (4 VGPRs)
typedef float f32x16 __attribute__((ext_vector_type(16)));   // MFMA 32x32 C/D fragment

#define HDIM 512
#define NHEAD 8
#define GNUM 64
#define CNUM 10
#define SLOPE 0.01f
#define BNEPS 1e-5f
#define PSPLIT 8

__device__ __forceinline__ float b2f(u16 u) { return __uint_as_float(((unsigned)u) << 16); }
__device__ __forceinline__ u16 f2b(float f) {              // RNE f32->bf16
    unsigned u = __float_as_uint(f);
    u += 0x7FFFu + ((u >> 16) & 1u);
    return (u16)(u >> 16);
}
__device__ __forceinline__ void splitbf(float v, u16& hi, u16& lo) {
    u16 h = f2b(v);
    hi = h;
    lo = f2b(v - b2f(h));
}

__global__ void sentinel_kernel(float* out, int n, float val) {
    int i = blockIdx.x * 256 + threadIdx.x;
    if (i < n) out[i] = val;
}

__global__ void zero_i32_kernel(int* __restrict__ p, int n) {
    int i = blockIdx.x * 256 + threadIdx.x;
    if (i < n) p[i] = 0;
}

// ---- zero the padded tail rows [N, N128) of all GEMM A-inputs ----
__global__ void ztail_kernel(u16* __restrict__ xinh, u16* __restrict__ xinl, int F0,
                             u16* __restrict__ x0h, u16* __restrict__ x0l,
                             u16* __restrict__ x1h, u16* __restrict__ x1l,
                             u16* __restrict__ x2h, u16* __restrict__ x2l,
                             u16* __restrict__ x3h, u16* __restrict__ x3l, int N) {
    int row = N + blockIdx.x;
    int b = blockIdx.y;
    int t = threadIdx.x;
    if (b < 2) {
        u16* p = (b == 0) ? xinh : xinl;
        for (int c = t; c < F0; c += 256) p[(size_t)row * F0 + c] = 0;
    } else {
        u16* ps[8] = {x0h, x0l, x1h, x1l, x2h, x2l, x3h, x3l};
        u16* p = ps[b - 2];
        for (int c = t; c < HDIM; c += 256) p[(size_t)row * HDIM + c] = 0;
    }
}

// ---- weight transpose+split via LDS tiles: W[K][512] f32 -> Whi/Wlo[n][K] bf16 ----
__device__ __forceinline__ void wsplit_body(const float* __restrict__ W, u16* __restrict__ Whi,
                                            u16* __restrict__ Wlo, int K) {
    __shared__ float tile[64][65];
    int kb = blockIdx.x * 64, nb = blockIdx.y * 64;
    int t = threadIdx.x;
    #pragma unroll
    for (int i = 0; i < 16; i++) {
        int idx = t + i * 256;
        int r = idx >> 6, c = idx & 63;
        tile[r][c] = W[(size_t)(kb + r) * HDIM + nb + c];
    }
    __syncthreads();
    #pragma unroll
    for (int i = 0; i < 16; i++) {
        int idx = t + i * 256;
        int r = idx >> 6, c = idx & 63;
        float v = tile[c][r];
        u16 hi, lo;
        splitbf(v, hi, lo);
        size_t o = (size_t)(nb + r) * K + kb + c;
        Whi[o] = hi;
        Wlo[o] = lo;
    }
}

__global__ void wsplit_kernel(const float* __restrict__ W, u16* __restrict__ Whi,
                              u16* __restrict__ Wlo, int K) {
    wsplit_body(W, Whi, Wlo, K);
}

__global__ void wsplit3_kernel(const float* __restrict__ W1, const float* __restrict__ W2,
                               const float* __restrict__ W3,
                               u16* __restrict__ h1, u16* __restrict__ l1,
                               u16* __restrict__ h2, u16* __restrict__ l2,
                               u16* __restrict__ h3, u16* __restrict__ l3) {
    const float* W = (blockIdx.z == 0) ? W1 : (blockIdx.z == 1) ? W2 : W3;
    u16* Wh = (blockIdx.z == 0) ? h1 : (blockIdx.z == 1) ? h2 : h3;
    u16* Wl = (blockIdx.z == 0) ? l1 : (blockIdx.z == 1) ? l2 : l3;
    wsplit_body(W, Wh, Wl, HDIM);
}

// ---- activation split: f32 -> hi/lo bf16 ----
__global__ void xsplit_kernel(const float* __restrict__ x, u16* __restrict__ hi,
                              u16* __restrict__ lo, int n) {
    int i = blockIdx.x * 256 + threadIdx.x;
    if (i < n) splitbf(x[i], hi[i], lo[i]);
}

// ---- split-bf16 MFMA GEMM (32x32x16), 64x64 tile, BK=32, 3-term, LDS-staged ----
// 128-thread blocks (2 waves): grid 157*8=1256 blocks ~= 4.9/CU (vs 2.47 at 256-thr/128-tile)
// so resident neighbors hide the barrier drain (m114). XCD swizzle keeps A L2-resident
// (verified FETCH 87->15MB). Each wave owns full 64-col rows -> es/ed reduced in-wave,
// no sE LDS, no third barrier. A rows tail-padded (ztail) -> guard-free staging.
__global__ __launch_bounds__(128, 2) void gemm_split(const u16* __restrict__ Ah,
                                                     const u16* __restrict__ Al,
                                                     const u16* __restrict__ Bh,
                                                     const u16* __restrict__ Bl,
                                                     const float* __restrict__ a_src,
                                                     const float* __restrict__ a_dst,
                                                     u16* __restrict__ Chi,
                                                     float* __restrict__ es,
                                                     float* __restrict__ ed, int M, int K) {
    __shared__ u16 sAh[64 * 40];   // [m][k], pad 40 (80B stride, 16B-aligned, verified pattern)
    __shared__ u16 sAl[64 * 40];
    __shared__ u16 sBh[64 * 40];   // [n][k]
    __shared__ u16 sBl[64 * 40];
    int t = threadIdx.x;
    int id = blockIdx.x;
    int nrt = gridDim.x >> 3;
    int w = (id & 7) * nrt + (id >> 3);
    int rt = w >> 3, ct = w & 7;
    int bm = rt * 64, bn = ct * 64;
    int hh = ct;                    // head index (64 cols per head)
    int wv = t >> 6, lane = t & 63;
    int wm = wv * 32;               // wave's 32-row band
    int l32 = lane & 31, kh = lane >> 5;

    // staging: 2 int4 chunks per array per thread (64 rows x 32 k = 256 chunks / 128 thr)
    int c0 = 2 * t, c1 = 2 * t + 1;
    int ar0 = c0 >> 2, ac0 = (c0 & 3) * 8;
    int ar1 = c1 >> 2, ac1 = (c1 & 3) * 8;

    f32x16 acc[2];                  // [n-tile]
    for (int m = 0; m < 2; m++)
        for (int r = 0; r < 16; r++) acc[m][r] = 0.f;

    const u16* Ahp0 = Ah + (size_t)(bm + ar0) * K + ac0;
    const u16* Alp0 = Al + (size_t)(bm + ar0) * K + ac0;
    const u16* Ahp1 = Ah + (size_t)(bm + ar1) * K + ac1;
    const u16* Alp1 = Al + (size_t)(bm + ar1) * K + ac1;
    const u16* Bhp0 = Bh + (size_t)(bn + ar0) * K + ac0;
    const u16* Blp0 = Bl + (size_t)(bn + ar0) * K + ac0;
    const u16* Bhp1 = Bh + (size_t)(bn + ar1) * K + ac1;
    const u16* Blp1 = Bl + (size_t)(bn + ar1) * K + ac1;

    for (int kt = 0; kt < K; kt += 32) {
        int4 vah0 = *(const int4*)(Ahp0 + kt);
        int4 val0 = *(const int4*)(Alp0 + kt);
        int4 vah1 = *(const int4*)(Ahp1 + kt);
        int4 val1 = *(const int4*)(Alp1 + kt);
        int4 vbh0 = *(const int4*)(Bhp0 + kt);
        int4 vbl0 = *(const int4*)(Blp0 + kt);
        int4 vbh1 = *(const int4*)(Bhp1 + kt);
        int4 vbl1 = *(const int4*)(Blp1 + kt);
        __syncthreads();
        *(int4*)&sAh[ar0 * 40 + ac0] = vah0;
        *(int4*)&sAl[ar0 * 40 + ac0] = val0;
        *(int4*)&sAh[ar1 * 40 + ac1] = vah1;
        *(int4*)&sAl[ar1 * 40 + ac1] = val1;
        *(int4*)&sBh[ar0 * 40 + ac0] = vbh0;
        *(int4*)&sBl[ar0 * 40 + ac0] = vbl0;
        *(int4*)&sBh[ar1 * 40 + ac1] = vbh1;
        *(int4*)&sBl[ar1 * 40 + ac1] = vbl1;
        __syncthreads();
        #pragma unroll
        for (int ks = 0; ks < 32; ks += 16) {
            int ko = ks + kh * 8;
            bfv8 a_h = *(bfv8*)&sAh[(wm + l32) * 40 + ko];
            bfv8 a_l = *(bfv8*)&sAl[(wm + l32) * 40 + ko];
            bfv8 b0h = *(bfv8*)&sBh[(l32) * 40 + ko];
            bfv8 b0l = *(bfv8*)&sBl[(l32) * 40 + ko];
            bfv8 b1h = *(bfv8*)&sBh[(32 + l32) * 40 + ko];
            bfv8 b1l = *(bfv8*)&sBl[(32 + l32) * 40 + ko];
            acc[0] = __builtin_amdgcn_mfma_f32_32x32x16_bf16(a_l, b0h, acc[0], 0, 0, 0);
            acc[0] = __builtin_amdgcn_mfma_f32_32x32x16_bf16(a_h, b0l, acc[0], 0, 0, 0);
            acc[0] = __builtin_amdgcn_mfma_f32_32x32x16_bf16(a_h, b0h, acc[0], 0, 0, 0);
            acc[1] = __builtin_amdgcn_mfma_f32_32x32x16_bf16(a_l, b1h, acc[1], 0, 0, 0);
            acc[1] = __builtin_amdgcn_mfma_f32_32x32x16_bf16(a_h, b1l, acc[1], 0, 0, 0);
            acc[1] = __builtin_amdgcn_mfma_f32_32x32x16_bf16(a_h, b1h, acc[1], 0, 0, 0);
        }
    }
    // epilogue: C write + in-wave es/ed (cols of this head split across acc[0]/acc[1])
    float asv0 = a_src[hh * 64 + l32];
    float asv1 = a_src[hh * 64 + 32 + l32];
    float adv0 = a_dst[hh * 64 + l32];
    float adv1 = a_dst[hh * 64 + 32 + l32];
    // C/D layout (m74/m101-verified): col=lane&31, row=(reg&3)+8*(reg>>2)+4*(lane>>5)
    #pragma unroll
    for (int r = 0; r < 16; r++) {
        int row = bm + wm + (r & 3) + 8 * (r >> 2) + 4 * kh;
        float v0 = acc[0][r], v1 = acc[1][r];
        if (row < M) {
            size_t o = (size_t)row * HDIM + bn;
            Chi[o + l32] = f2b(v0);
            Chi[o + 32 + l32] = f2b(v1);
        }
        float s1 = v0 * asv0 + v1 * asv1;
        float s2 = v0 * adv0 + v1 * adv1;
        #pragma unroll
        for (int msk = 1; msk <= 16; msk <<= 1) {
            s1 += __shfl_xor(s1, msk);
            s2 += __shfl_xor(s2, msk);
        }
        if (l32 == 0 && row < M) {
            es[row * NHEAD + hh] = s1;
            ed[row * NHEAD + hh] = s2;
        }
    }
}

// ---- counting sort of edges by dst ----
__global__ void hist_kernel(const int* __restrict__ ei, int* __restrict__ deg, int E) {
    int e = blockIdx.x * 256 + threadIdx.x;
    if (e < E) atomicAdd(&deg[ei[E + e]], 1);
}

__global__ void scan_kernel(const int* __restrict__ deg, int* __restrict__ offs,
                            int* __restrict__ cursor, int n) {
    __shared__ int lds[1024];
    int t = threadIdx.x;
    const int CH = 16;
    int base = t * CH;
    int local[CH];
    int s = 0;
    for (int i = 0; i < CH; i++) {
        int idx = base + i;
        local[i] = (idx < n) ? deg[idx] : 0;
        s += local[i];
    }
    lds[t] = s;
    __syncthreads();
    for (int off = 1; off < 1024; off <<= 1) {
        int v = lds[t];
        int add = (t >= off) ? lds[t - off] : 0;
        __syncthreads();
        lds[t] = v + add;
        __syncthreads();
    }
    int ex = (t == 0) ? 0 : lds[t - 1];
    for (int i = 0; i < CH; i++) {
        int idx = base + i;
        if (idx < n) { offs[idx] = ex; cursor[idx] = ex; ex += local[i]; }
    }
}

__global__ void scatter_kernel(const int* __restrict__ ei, int* __restrict__ cursor,
                               int* __restrict__ ssrc, int E) {
    int e = blockIdx.x * 256 + threadIdx.x;
    if (e < E) {
        int p = atomicAdd(&cursor[ei[E + e]], 1);
        ssrc[p] = ei[e];
    }
}

// ---- fused per-dst ONLINE softmax + aggregation + bias + ELU (+ residual), unroll x4 ----
__global__ void agg_kernel(const u16* __restrict__ hh_buf, const float* __restrict__ es,
                           const float* __restrict__ ed, const int* __restrict__ offs,
                           const int* __restrict__ deg, const int* __restrict__ ssrc,
                           const float* __restrict__ bias,
                           u16* __restrict__ ohi, u16* __restrict__ olo,
                           const u16* __restrict__ rhi, const u16* __restrict__ rlo,
                           u16* __restrict__ qhi, u16* __restrict__ qlo, int n) {
    int node = blockIdx.x * 4 + (threadIdx.x >> 6);
    int lane = threadIdx.x & 63;
    if (node >= n) return;
    int hh = lane >> 3, f = lane * 8;
    float edv = ed[node * NHEAD + hh];
    int st = offs[node], cnt = deg[node];

    float m = -INFINITY, den = 0.f;
    float acc[8] = {0.f, 0.f, 0.f, 0.f, 0.f, 0.f, 0.f, 0.f};
    int i = 0;
    for (; i + 4 <= cnt; i += 4) {
        int s0 = ssrc[st + i], s1 = ssrc[st + i + 1];
        int s2i = ssrc[st + i + 2], s3 = ssrc[st + i + 3];
        float e0 = es[s0 * NHEAD + hh] + edv;
        float e1 = es[s1 * NHEAD + hh] + edv;
        float e2 = es[s2i * NHEAD + hh] + edv;
        float e3 = es[s3 * NHEAD + hh] + edv;
        union { int4 v; u16 u[8]; } U0, U1, U2, U3;
        U0.v = *(const int4*)(hh_buf + (size_t)s0 * HDIM + f);
        U1.v = *(const int4*)(hh_buf + (size_t)s1 * HDIM + f);
        U2.v = *(const int4*)(hh_buf + (size_t)s2i * HDIM + f);
        U3.v = *(const int4*)(hh_buf + (size_t)s3 * HDIM + f);
        e0 = e0 > 0.f ? e0 : SLOPE * e0;
        e1 = e1 > 0.f ? e1 : SLOPE * e1;
        e2 = e2 > 0.f ? e2 : SLOPE * e2;
        e3 = e3 > 0.f ? e3 : SLOPE * e3;
        float mn = fmaxf(fmaxf(m, fmaxf(e0, e1)), fmaxf(e2, e3));
        float sc = __expf(m - mn);
        float w0 = __expf(e0 - mn), w1 = __expf(e1 - mn);
        float w2 = __expf(e2 - mn), w3 = __expf(e3 - mn);
        den = den * sc + w0 + w1 + w2 + w3;
        #pragma unroll
        for (int j = 0; j < 8; j++)
            acc[j] = acc[j] * sc + w0 * b2f(U0.u[j]) + w1 * b2f(U1.u[j])
                                 + w2 * b2f(U2.u[j]) + w3 * b2f(U3.u[j]);
        m = mn;
    }
    for (; i < cnt; i++) {
        int s0 = ssrc[st + i];
        float e0 = es[s0 * NHEAD + hh] + edv;
        union { int4 v; u16 u[8]; } U0;
        U0.v = *(const int4*)(hh_buf + (size_t)s0 * HDIM + f);
        e0 = e0 > 0.f ? e0 : SLOPE * e0;
        float mn = fmaxf(m, e0);
        float sc = __expf(m - mn);
        float w0 = __expf(e0 - mn);
        den = den * sc + w0;
        #pragma unroll
        for (int j = 0; j < 8; j++) acc[j] = acc[j] * sc + w0 * b2f(U0.u[j]);
        m = mn;
    }
    float inv = den > 0.f ? 1.f / den : 0.f;
    union { int4 v; u16 u[8]; } Hi, Lo;
    float o[8];
    #pragma unroll
    for (int j = 0; j < 8; j++) {
        float v = acc[j] * inv + bias[f + j];
        o[j] = v > 0.f ? v : __expf(v) - 1.f;  // ELU
        splitbf(o[j], Hi.u[j], Lo.u[j]);
    }
    size_t base = (size_t)node * HDIM + f;
    *(int4*)&ohi[base] = Hi.v;
    *(int4*)&olo[base] = Lo.v;
    if (rhi) {
        union { int4 v; u16 u[8]; } Rh, Rl, Qh, Ql;
        Rh.v = *(const int4*)&rhi[base];
        Rl.v = *(const int4*)&rlo[base];
        #pragma unroll
        for (int j = 0; j < 8; j++) {
            float v = o[j] + b2f(Rh.u[j]) + b2f(Rl.u[j]);
            splitbf(v, Qh.u[j], Ql.u[j]);
        }
        *(int4*)&qhi[base] = Qh.v;
        *(int4*)&qlo[base] = Ql.v;
    }
}

// ---- pooling stage 1: partial segment-max over bf16-hi ----
__global__ void pool1_kernel(const u16* __restrict__ s0h, const u16* __restrict__ s1h,
                             const u16* __restrict__ s2h, const u16* __restrict__ s3h,
                             const int* __restrict__ batch, float* __restrict__ partial, int n) {
    int g = blockIdx.x, b = blockIdx.y, c = blockIdx.z;
    int t = threadIdx.x;
    const u16* hs[4] = {s0h, s1h, s2h, s3h};
    const u16* sh = hs[b];
    int lo = 0, hi = n;
    while (lo < hi) { int mid = (lo + hi) >> 1; if (batch[mid] < g) lo = mid + 1; else hi = mid; }
    int start = lo;
    lo = start; hi = n;
    while (lo < hi) { int mid = (lo + hi) >> 1; if (batch[mid] < g + 1) lo = mid + 1; else hi = mid; }
    int end = lo;
    int len = end - start;
    int cb = start + (int)(((long long)len * c) / PSPLIT);
    int ce = start + (int)(((long long)len * (c + 1)) / PSPLIT);
    float mx0 = -INFINITY, mx1 = -INFINITY;
    for (int i = cb; i < ce; i++) {
        size_t ro = (size_t)i * HDIM;
        mx0 = fmaxf(mx0, b2f(sh[ro + t]));
        mx1 = fmaxf(mx1, b2f(sh[ro + 256 + t]));
    }
    size_t pb = (size_t)((g * 4 + b) * PSPLIT + c) * 512;
    partial[pb + t] = mx0;
    partial[pb + 256 + t] = mx1;
}

// ---- pooling stage 2: reduce PSPLIT partials, clamp empties; fused z init ----
__global__ void pool2_kernel(const float* __restrict__ partial, float* __restrict__ pooled,
                             const float* __restrict__ mb1, float* __restrict__ z) {
    int g = blockIdx.x, b = blockIdx.y;
    int t = threadIdx.x;
    float mx0 = -INFINITY, mx1 = -INFINITY;
    for (int c = 0; c < PSPLIT; c++) {
        size_t pb = (size_t)((g * 4 + b) * PSPLIT + c) * 512;
        mx0 = fmaxf(mx0, partial[pb + t]);
        mx1 = fmaxf(mx1, partial[pb + 256 + t]);
    }
    if (!isfinite(mx0)) mx0 = 0.f;
    if (!isfinite(mx1)) mx1 = 0.f;
    pooled[g * 2048 + b * 512 + t] = mx0;
    pooled[g * 2048 + b * 512 + 256 + t] = mx1;
    if (t < 128) {
        int col = b * 128 + t;
        z[g * HDIM + col] = mb1[col];
    }
}

// ---- MLP layer 1, split-K: z[64,512] += pooled[64,2048-chunk] @ mW1-chunk ----
__global__ __launch_bounds__(256) void mlp1_splitk(const float* __restrict__ pooled,
                                                   const float* __restrict__ mW1,
                                                   float* __restrict__ z) {
    __shared__ float sp[256];
    int g = blockIdx.x, kc = blockIdx.y * 256;
    int t = threadIdx.x;
    sp[t] = pooled[g * 2048 + kc + t];
    __syncthreads();
    float acc0 = 0.f, acc1 = 0.f;
    const float* wp = mW1 + (size_t)kc * HDIM;
    #pragma unroll 8
    for (int k = 0; k < 256; k++) {
        float pv = sp[k];
        acc0 += pv * wp[(size_t)k * HDIM + t];
        acc1 += pv * wp[(size_t)k * HDIM + 256 + t];
    }
    atomicAdd(&z[g * HDIM + t], acc0);
    atomicAdd(&z[g * HDIM + 256 + t], acc1);
}

// ---- BatchNorm (batch stats over 64 graphs) + ReLU ----
__global__ void bn_relu_kernel(const float* __restrict__ z, const float* __restrict__ gammaf,
                               const float* __restrict__ betaf, float* __restrict__ zn) {
    int col = blockIdx.x;
    int g = threadIdx.x;   // 64 = one wave
    float v = z[g * HDIM + col];
    float s = v;
    for (int o = 32; o > 0; o >>= 1) s += __shfl_xor(s, o);
    float mu = s * (1.f / 64.f);
    float d = v - mu;
    float s2 = d * d;
    for (int o = 32; o > 0; o >>= 1) s2 += __shfl_xor(s2, o);
    float var = s2 * (1.f / 64.f);
    float o = d * rsqrtf(var + BNEPS) * gammaf[col] + betaf[col];
    zn[g * HDIM + col] = fmaxf(o, 0.f);
}

// ---- final: out[g][c] = zn[g,:] . mW2[:,c] + mb2[c]; one wave per output ----
__global__ void final_kernel(const float* __restrict__ zn, const float* __restrict__ mW2,
                             const float* __restrict__ mb2, float* __restrict__ out) {
    int g = blockIdx.x, c = blockIdx.y;
    int lane = threadIdx.x;   // 64
    float acc = 0.f;
    #pragma unroll
    for (int k = lane; k < HDIM; k += 64) acc += zn[g * HDIM + k] * mW2[k * CNUM + c];
    for (int o = 32; o > 0; o >>= 1) acc += __shfl_down(acc, o);
    if (lane == 0) out[g * CNUM + c] = acc + mb2[c];
}

extern "C" void kernel_launch(void* const* d_in, const int* in_sizes, int n_in,
                              void* d_out, int out_size, void* d_ws, size_t ws_size,
                              hipStream_t stream) {
    const float* x = (const float*)d_in[0];
    const int* ei = (const int*)d_in[1];
    const int* batch = (const int*)d_in[2];
    const float* Wm[4] = {(const float*)d_in[3], (const float*)d_in[7],
                          (const float*)d_in[11], (const float*)d_in[15]};
    const float* Asc[4] = {(const float*)d_in[4], (const float*)d_in[8],
                           (const float*)d_in[12], (const float*)d_in[16]};
    const float* Adc[4] = {(const float*)d_in[5], (const float*)d_in[9],
                           (const float*)d_in[13], (const float*)d_in[17]};
    const float* Bb[4] = {(const float*)d_in[6], (const float*)d_in[10],
                          (const float*)d_in[14], (const float*)d_in[18]};
    const float* mW1 = (const float*)d_in[19];
    const float* mb1 = (const float*)d_in[20];
    const float* gammaf = (const float*)d_in[21];
    const float* betaf = (const float*)d_in[22];
    const float* mW2 = (const float*)d_in[23];
    const float* mb2 = (const float*)d_in[24];
    (void)n_in;

    int N = in_sizes[2];
    int E = in_sizes[1] / 2;
    int F0 = in_sizes[0] / N;
    int N128 = ((N + 127) / 128) * 128;                 // padded rows (covers 64-tiles too)
    int nrt = (N + 63) / 64;                            // 64-row tiles

    // ---- workspace carve (256B-aligned) ----
    char* p = (char*)d_ws;
    auto alloc = [&](size_t bytes) -> char* {
        char* r = p;
        p += (bytes + 255) & ~(size_t)255;
        return r;
    };
    u16 *Wh[4], *Wl[4];
    Wh[0] = (u16*)alloc((size_t)HDIM * F0 * 2);
    Wl[0] = (u16*)alloc((size_t)HDIM * F0 * 2);
    for (int l = 1; l < 4; l++) {
        Wh[l] = (u16*)alloc((size_t)HDIM * HDIM * 2);
        Wl[l] = (u16*)alloc((size_t)HDIM * HDIM * 2);
    }
    u16* xinh = (u16*)alloc((size_t)N128 * F0 * 2);
    u16* xinl = (u16*)alloc((size_t)N128 * F0 * 2);
    u16* hhi = (u16*)alloc((size_t)N * HDIM * 2);       // h of current layer (bf16-hi only)
    u16 *xh[4], *xl[4];                                 // x0..x3 as hi/lo bf16 pairs (padded)
    for (int l = 0; l < 4; l++) {
        xh[l] = (u16*)alloc((size_t)N128 * HDIM * 2);
        xl[l] = (u16*)alloc((size_t)N128 * HDIM * 2);
    }
    float* es = (float*)alloc((size_t)N * NHEAD * 4);
    float* ed = (float*)alloc((size_t)N * NHEAD * 4);
    int* deg = (int*)alloc((size_t)N * 4);
    int* offs = (int*)alloc((size_t)N * 4);
    int* cursor = (int*)alloc((size_t)N * 4);
    int* ssrc = (int*)alloc((size_t)E * 4);
    float* partial = (float*)alloc((size_t)GNUM * 4 * PSPLIT * 512 * 4);
    float* pooled = (float*)alloc((size_t)GNUM * 4 * HDIM * 4);
    float* z = (float*)alloc((size_t)GNUM * HDIM * 4);
    float* zn = (float*)alloc((size_t)GNUM * HDIM * 4);

    if ((size_t)(p - (char*)d_ws) > ws_size) {
        sentinel_kernel<<<(out_size + 255) / 256, 256, 0, stream>>>((float*)d_out, out_size, 999.f);
        return;
    }

    // ---- weight transpose+split, input split, tail zero ----
    {
        dim3 wg0(F0 / 64, HDIM / 64);
        wsplit_kernel<<<wg0, 256, 0, stream>>>(Wm[0], Wh[0], Wl[0], F0);
        dim3 wg3(HDIM / 64, HDIM / 64, 3);
        wsplit3_kernel<<<wg3, 256, 0, stream>>>(Wm[1], Wm[2], Wm[3],
                                                Wh[1], Wl[1], Wh[2], Wl[2], Wh[3], Wl[3]);
    }
    xsplit_kernel<<<(N * F0 + 255) / 256, 256, 0, stream>>>(x, xinh, xinl, N * F0);
    if (N128 > N) {
        dim3 zt(N128 - N, 10);
        ztail_kernel<<<zt, 256, 0, stream>>>(xinh, xinl, F0, xh[0], xl[0], xh[1], xl[1],
                                             xh[2], xl[2], xh[3], xl[3], N);
    }

    // ---- counting sort of edges by dst ----
    zero_i32_kernel<<<(N + 255) / 256, 256, 0, stream>>>(deg, N);
    hist_kernel<<<(E + 255) / 256, 256, 0, stream>>>(ei, deg, E);
    scan_kernel<<<1, 1024, 0, stream>>>(deg, offs, cursor, N);
    scatter_kernel<<<(E + 255) / 256, 256, 0, stream>>>(ei, cursor, ssrc, E);

    // ---- 4 GAT layers ----
    const u16* linh[4] = {xinh, xh[0], xh[1], xh[3]};
    const u16* linl[4] = {xinl, xl[0], xl[1], xl[3]};
    int lK[4] = {F0, HDIM, HDIM, HDIM};
    // layer outputs: L0->x0, L1->x1, L2->x2 (+x3 residual), L3->xt (aliases x0, dead)
    u16* louth[4] = {xh[0], xh[1], xh[2], xh[0]};
    u16* loutl[4] = {xl[0], xl[1], xl[2], xl[0]};
    int gemm_blocks = nrt * 8;                          // 1-D, XCD-swizzled inside
    int agg_blocks = (N + 3) / 4;
    for (int L = 0; L < 4; L++) {
        gemm_split<<<gemm_blocks, 128, 0, stream>>>(linh[L], linl[L], Wh[L], Wl[L],
                                                    Asc[L], Adc[L], hhi, es, ed, N, lK[L]);
        const u16* rh = (L == 2) ? xh[0] : nullptr;
        const u16* rl = (L == 2) ? xl[0] : nullptr;
        u16* qh = (L == 2) ? xh[3] : nullptr;
        u16* ql = (L == 2) ? xl[3] : nullptr;
        agg_kernel<<<agg_blocks, 256, 0, stream>>>(hhi, es, ed, offs, deg, ssrc, Bb[L],
                                                   louth[L], loutl[L], rh, rl, qh, ql, N);
    }

    // ---- pooling (two-stage, hi-only): concat order (xt, x1, x2, x3) ----
    dim3 pool1_grid(GNUM, 4, PSPLIT);
    pool1_kernel<<<pool1_grid, 256, 0, stream>>>(xh[0], xh[1], xh[2], xh[3],
                                                 batch, partial, N);
    dim3 pool2_grid(GNUM, 4);
    pool2_kernel<<<pool2_grid, 256, 0, stream>>>(partial, pooled, mb1, z);

    // ---- MLP head: split-K accumulate, BN+ReLU, final ----
    dim3 mlp_grid(GNUM, 8);
    mlp1_splitk<<<mlp_grid, 256, 0, stream>>>(pooled, mW1, z);
    bn_relu_kernel<<<HDIM, 64, 0, stream>>>(z, gammaf, betaf, zn);
    dim3 final_grid(GNUM, CNUM);
    final_kernel<<<final_grid, 64, 0, stream>>>(zn, mW2, mb2, (float*)d_out);
}